// Round 10
// baseline (89.246 us; speedup 1.0000x reference)
//
#include <hip/hip_runtime.h>

#define BATCH  4
#define NPTS   4096
#define NSKEL  100
#define KNN    10
#define QPB    32                 // queries per block (16 pairs x 2)
#define CPT    64                 // candidates per thread
#define NG4    16                 // float4 groups per chunk
#define BIG    3.0e38f

__device__ __forceinline__ float med3f(float a, float b, float c) {
#if __has_builtin(__builtin_amdgcn_fmed3f)
    return __builtin_amdgcn_fmed3f(a, b, c);
#else
    float d;
    asm("v_med3_f32 %0, %1, %2, %3" : "=v"(d) : "v"(a), "v"(b), "v"(c));
    return d;
#endif
}

#define CE(a,i,j) do { float _lo = fminf(a[i],a[j]); a[j] = fmaxf(a[i],a[j]); a[i] = _lo; } while (0)
#define SORT10(c) do { \
    CE(c,0,8); CE(c,1,9); \
    CE(c,2,6); CE(c,3,7); CE(c,4,8); CE(c,5,9); \
    CE(c,2,4); CE(c,3,5); CE(c,6,8); CE(c,7,9); CE(c,0,1); \
    CE(c,2,3); CE(c,4,5); CE(c,6,7); CE(c,8,9); } while (0)

// Bitonic half-cleaner merge of two ascending 10-lists (keep 10 smallest)
// + 15-CE re-sort. Validated R3-R9 (absmax 0).
__device__ __forceinline__ void merge_round(float l[KNN], int mask) {
    float c[KNN];
#pragma unroll
    for (int i = 0; i < KNN; ++i) {
        float o = __shfl_xor(l[KNN - 1 - i], mask, 64);
        c[i] = fminf(l[i], o);
    }
    SORT10(c);
#pragma unroll
    for (int i = 0; i < KNN; ++i) l[i] = c[i];
}

__global__ __launch_bounds__(1024, 8) void voronoi_kernel(const float* __restrict__ xyz,
                                                          const float* __restrict__ skel,
                                                          float* __restrict__ out) {
    __shared__ float sx[NPTS], sy[NPTS], sz[NPTS];   // SoA positions, 48 KB
    __shared__ float4 sskl[NSKEL];                    // 1.6 KB
    __shared__ float  qlists[QPB][KNN];               // 1.25 KB (merge + final)
    __shared__ float  part[16];

    const int tid = threadIdx.x;
    const int b   = blockIdx.x >> 7;            // 128 blocks per batch
    const int qb  = (blockIdx.x & 127) * QPB;   // 32 queries per block
    const float* xb = xyz  + (size_t)b * NPTS * 6;
    const float* sb = skel + (size_t)b * NSKEL * 3;

    // Stage 2 points per iter via 3 coalesced float4 loads
    for (int p2 = tid; p2 < NPTS / 2; p2 += 1024) {
        const float4* row = (const float4*)(xb + p2 * 12);
        float4 A = row[0], Bv = row[1], Cv = row[2];
        int i0 = 2 * p2;
        sx[i0]   = A.x;  sy[i0]   = A.y;  sz[i0]   = A.z;
        sx[i0+1] = Bv.z; sy[i0+1] = Bv.w; sz[i0+1] = Cv.x;
    }
    if (tid < NSKEL) {
        float x = sb[tid*3+0], y = sb[tid*3+1], z = sb[tid*3+2];
        sskl[tid] = make_float4(x, y, z, x*x + y*y + z*z);
    }
    __syncthreads();

    const int split = tid & 31;
    const int group = tid >> 5;            // 0..31
    const int half  = group >> 4;          // candidate half
    const int qpair = group & 15;          // query-pair id
    const int q0i   = qb + qpair * 2;
    // score = |c|^2 - 2 q.c (monotone map of d2; d2 gap == score gap)
    const float n0x = -2.f*sx[q0i],   n0y = -2.f*sy[q0i],   n0z = -2.f*sz[q0i];
    const float n1x = -2.f*sx[q0i+1], n1y = -2.f*sy[q0i+1], n1z = -2.f*sz[q0i+1];

    float l0[KNN], l1[KNN];
#pragma unroll
    for (int k = 0; k < KNN; ++k) { l0[k] = BIG; l1[k] = BIG; }

    const int ch = split + (half << 5);    // chunk 0..63
    const int jb = ch * CPT;
    const float4* sx4 = (const float4*)(sx + jb);
    const float4* sy4 = (const float4*)(sy + jb);
    const float4* sz4 = (const float4*)(sz + jb);

    auto PROC = [&](float4 xv, float4 yv, float4 zv, int t) {
        const int j0 = jb + ((t + split) & 15) * 4;
#pragma unroll
        for (int u = 0; u < 4; ++u) {
            float x = ((const float*)&xv)[u];
            float y = ((const float*)&yv)[u];
            float z = ((const float*)&zv)[u];
            float w  = fmaf(z, z, fmaf(y, y, x * x));
            float s0 = fmaf(n0z, z, fmaf(n0y, y, fmaf(n0x, x, w)));
            float s1 = fmaf(n1z, z, fmaf(n1y, y, fmaf(n1x, x, w)));
            unsigned j = (unsigned)(j0 + u);
            float f0 = __uint_as_float((__float_as_uint(s0) & 0xFFFFF000u) | j);
            float f1 = __uint_as_float((__float_as_uint(s1) & 0xFFFFF000u) | j);
#pragma unroll
            for (int k = KNN - 1; k >= 1; --k) l0[k] = med3f(f0, l0[k-1], l0[k]);
            l0[0] = fminf(f0, l0[0]);
#pragma unroll
            for (int k = KNN - 1; k >= 1; --k) l1[k] = med3f(f1, l1[k-1], l1[k]);
            l1[0] = fminf(f1, l1[0]);
        }
    };

    // Double-buffered scan over this half's 64 candidates (rotated visit
    // order keeps each 16-lane phase on distinct bank-quads).
    {
        int g0 = split & 15;
        float4 XA = sx4[g0], YA = sy4[g0], ZA = sz4[g0];
#pragma unroll 1
        for (int t = 0; t < NG4; t += 2) {
            int g1 = (t + 1 + split) & 15;
            float4 XB = sx4[g1], YB = sy4[g1], ZB = sz4[g1];
            PROC(XA, YA, ZA, t);
            if (t + 2 < NG4) {
                int g2 = (t + 2 + split) & 15;
                XA = sx4[g2]; YA = sy4[g2]; ZA = sz4[g2];
            }
            PROC(XB, YB, ZB, t + 1);
        }
    }

    // ---- in-wave merge: 1 paired round, parity select, 4 single rounds ----
    merge_round(l0, 1);
    merge_round(l1, 1);
    const int sel = split & 1;
    float ml[KNN];
#pragma unroll
    for (int k = 0; k < KNN; ++k) ml[k] = sel ? l1[k] : l0[k];
    merge_round(ml, 2); merge_round(ml, 4); merge_round(ml, 8); merge_round(ml, 16);
    // even lanes hold (half's) q0 top-10, odd lanes q1's (sorted)

    // ---- cross-half merge in-place in qlists (lanes 0,1 of each group) ----
    if (half == 1 && split < 2) {
#pragma unroll
        for (int k = 0; k < KNN; ++k) qlists[qpair * 2 + split][k] = ml[k];
    }
    __syncthreads();
    if (half == 0 && split < 2) {
        float c[KNN];
#pragma unroll
        for (int i = 0; i < KNN; ++i)
            c[i] = fminf(ml[i], qlists[qpair * 2 + split][KNN - 1 - i]);
        SORT10(c);
#pragma unroll
        for (int k = 0; k < KNN; ++k) qlists[qpair * 2 + split][k] = c[k];
    }
    __syncthreads();

    // ---- epilogue: one query per group (32 groups = 32 queries) ----
    const int qi = qb + group;
    const float eqx = -2.f*sx[qi], eqy = -2.f*sy[qi], eqz = -2.f*sz[qi];

    // distributed changingrate: lanes 0..9 handle one neighbor each
    float crk = 0.0f;
    if (split < KNN) {
        int j = (int)(__float_as_uint(qlists[group][split]) & 0xFFFu);
        float nx = xb[qi*6+3], ny = xb[qi*6+4], nz = xb[qi*6+5];
        float mx = xb[j*6+3],  my_ = xb[j*6+4],  mz = xb[j*6+5];
        float cx = ny*mz - nz*my_;
        float cy = nz*mx - nx*mz;
        float cz = nx*my_ - ny*mx;
        float c1 = sqrtf(cx*cx + cy*cy + cz*cz);
        float px = nx*mx, py = ny*my_, pz = nz*mz;
        float c2 = sqrtf(px*px + py*py + pz*pz);
        crk = fminf(c1, c2);
    }
#pragma unroll
    for (int m = 1; m <= 8; m <<= 1) crk += __shfl_xor(crk, m, 64);

    // top-2 skeleton scores for qi (32-lane split)
    float t0v = BIG, t1v = BIG;
    for (int m = split; m < NSKEL; m += 32) {
        float4 c = sskl[m];
        float s = fmaf(eqz, c.z, fmaf(eqy, c.y, fmaf(eqx, c.x, c.w)));
        t1v = med3f(s, t0v, t1v);    // uses old t0v
        t0v = fminf(s, t0v);
    }
#pragma unroll
    for (int m = 1; m <= 16; m <<= 1) {
        float o0 = __shfl_xor(t0v, m, 64);
        float o1 = __shfl_xor(t1v, m, 64);
        float nv = fminf(fmaxf(t0v, o0), fminf(t1v, o1));
        t0v = fminf(t0v, o0); t1v = nv;
    }
    // d2 gap == score gap (|q|^2 cancels); owner: split 0 of each group
    float contrib = (split == 0) ? crk * (t1v - t0v) : 0.0f;
    contrib += __shfl_down(contrib, 32);   // combine the wave's 2 groups
    if ((tid & 63) == 0) part[tid >> 6] = contrib;
    __syncthreads();
    if (tid == 0) {
        float s = 0.0f;
#pragma unroll
        for (int i = 0; i < 16; ++i) s += part[i];
        atomicAdd(out, s);
    }

    // ---- skeleton self-NN term, one block per batch ----
    if ((blockIdx.x & 127) == 0) {
        float v = 0.0f;
        if (tid < NSKEL) {
            float4 sq = sskl[tid];
            float b0 = BIG, b1 = BIG; int i0 = 0, i1 = 0;
            for (int jj = 0; jj < NSKEL; ++jj) {
                float4 c = sskl[jj];
                float s = c.w - 2.0f*(sq.x*c.x + sq.y*c.y + sq.z*c.z);
                if (s < b0)      { b1 = b0; i1 = i0; b0 = s; i0 = jj; }
                else if (s < b1) { b1 = s; i1 = jj; }
            }
            float4 c = sskl[i1];                 // knn_skele[..., 1]
            float dx = sq.x - c.x, dy = sq.y - c.y, dz = sq.z - c.z;
            v = sqrtf(dx*dx + dy*dy + dz*dz);
        }
#pragma unroll
        for (int o = 32; o > 0; o >>= 1) v += __shfl_down(v, o);
        if ((tid & 63) == 0 && tid < 128) atomicAdd(out, -0.5f * v);
    }
}

extern "C" void kernel_launch(void* const* d_in, const int* in_sizes, int n_in,
                              void* d_out, int out_size, void* d_ws, size_t ws_size,
                              hipStream_t stream) {
    const float* xyz  = (const float*)d_in[0];
    // d_in[1] = num_class (== NSKEL), compile-time constant here
    const float* skel = (const float*)d_in[2];
    float* out = (float*)d_out;

    hipMemsetAsync(out, 0, sizeof(float), stream);
    voronoi_kernel<<<BATCH * 128, 1024, 0, stream>>>(xyz, skel, out);
}

// Round 11
// 61.804 us; speedup vs baseline: 1.4440x; 1.4440x over previous
//
#include <hip/hip_runtime.h>

#define BATCH  4
#define NPTS   4096
#define NSKEL  100
#define KNN    10
#define QPB    32                 // queries per block (16 pairs x 2)
#define CPT    64                 // candidates per thread
#define NG4    16                 // float4 groups per chunk
#define BIG    3.0e38f

__device__ __forceinline__ float med3f(float a, float b, float c) {
#if __has_builtin(__builtin_amdgcn_fmed3f)
    return __builtin_amdgcn_fmed3f(a, b, c);
#else
    float d;
    asm("v_med3_f32 %0, %1, %2, %3" : "=v"(d) : "v"(a), "v"(b), "v"(c));
    return d;
#endif
}

#define CE(a,i,j) do { float _lo = fminf(a[i],a[j]); a[j] = fmaxf(a[i],a[j]); a[i] = _lo; } while (0)
#define SORT10(c) do { \
    CE(c,0,8); CE(c,1,9); \
    CE(c,2,6); CE(c,3,7); CE(c,4,8); CE(c,5,9); \
    CE(c,2,4); CE(c,3,5); CE(c,6,8); CE(c,7,9); CE(c,0,1); \
    CE(c,2,3); CE(c,4,5); CE(c,6,7); CE(c,8,9); } while (0)

// Bitonic half-cleaner merge of two ascending 10-lists (keep 10 smallest)
// + 15-CE re-sort. Validated R3-R10 (absmax 0).
__device__ __forceinline__ void merge_round(float l[KNN], int mask) {
    float c[KNN];
#pragma unroll
    for (int i = 0; i < KNN; ++i) {
        float o = __shfl_xor(l[KNN - 1 - i], mask, 64);
        c[i] = fminf(l[i], o);
    }
    SORT10(c);
#pragma unroll
    for (int i = 0; i < KNN; ++i) l[i] = c[i];
}

// NOTE: min-waves/EU = 4 (NOT 8): the 8 setting caps VGPR at 64 and the
// allocator responds by compiling to 32 VGPR + massive scratch spill
// (R8/R10: WRITE_SIZE ~120-160 MB). At (1024,4) this structure compiles
// to ~44 VGPR spill-free (R9), which is <=64 so the HARDWARE still
// co-resides 2 blocks/CU given LDS fits (52 KB here -> 104 KB/CU).
__global__ __launch_bounds__(1024, 4) void voronoi_kernel(const float* __restrict__ xyz,
                                                          const float* __restrict__ skel,
                                                          float* __restrict__ out) {
    __shared__ float sx[NPTS], sy[NPTS], sz[NPTS];   // SoA positions, 48 KB
    __shared__ float4 sskl[NSKEL];                    // 1.6 KB
    __shared__ float  qlists[QPB][KNN];               // 1.25 KB (merge + final)
    __shared__ float  part[16];

    const int tid = threadIdx.x;
    const int b   = blockIdx.x >> 7;            // 128 blocks per batch
    const int qb  = (blockIdx.x & 127) * QPB;   // 32 queries per block
    const float* xb = xyz  + (size_t)b * NPTS * 6;
    const float* sb = skel + (size_t)b * NSKEL * 3;

    // Stage 2 points per iter via 3 coalesced float4 loads
    for (int p2 = tid; p2 < NPTS / 2; p2 += 1024) {
        const float4* row = (const float4*)(xb + p2 * 12);
        float4 A = row[0], Bv = row[1], Cv = row[2];
        int i0 = 2 * p2;
        sx[i0]   = A.x;  sy[i0]   = A.y;  sz[i0]   = A.z;
        sx[i0+1] = Bv.z; sy[i0+1] = Bv.w; sz[i0+1] = Cv.x;
    }
    if (tid < NSKEL) {
        float x = sb[tid*3+0], y = sb[tid*3+1], z = sb[tid*3+2];
        sskl[tid] = make_float4(x, y, z, x*x + y*y + z*z);
    }
    __syncthreads();

    const int split = tid & 31;
    const int group = tid >> 5;            // 0..31
    const int half  = group >> 4;          // candidate half
    const int qpair = group & 15;          // query-pair id
    const int q0i   = qb + qpair * 2;
    // score = |c|^2 - 2 q.c (monotone map of d2; d2 gap == score gap)
    const float n0x = -2.f*sx[q0i],   n0y = -2.f*sy[q0i],   n0z = -2.f*sz[q0i];
    const float n1x = -2.f*sx[q0i+1], n1y = -2.f*sy[q0i+1], n1z = -2.f*sz[q0i+1];

    float l0[KNN], l1[KNN];
#pragma unroll
    for (int k = 0; k < KNN; ++k) { l0[k] = BIG; l1[k] = BIG; }

    const int ch = split + (half << 5);    // chunk 0..63
    const int jb = ch * CPT;
    const float4* sx4 = (const float4*)(sx + jb);
    const float4* sy4 = (const float4*)(sy + jb);
    const float4* sz4 = (const float4*)(sz + jb);

    auto PROC = [&](float4 xv, float4 yv, float4 zv, int t) {
        const int j0 = jb + ((t + split) & 15) * 4;
#pragma unroll
        for (int u = 0; u < 4; ++u) {
            float x = ((const float*)&xv)[u];
            float y = ((const float*)&yv)[u];
            float z = ((const float*)&zv)[u];
            float w  = fmaf(z, z, fmaf(y, y, x * x));
            float s0 = fmaf(n0z, z, fmaf(n0y, y, fmaf(n0x, x, w)));
            float s1 = fmaf(n1z, z, fmaf(n1y, y, fmaf(n1x, x, w)));
            unsigned j = (unsigned)(j0 + u);
            float f0 = __uint_as_float((__float_as_uint(s0) & 0xFFFFF000u) | j);
            float f1 = __uint_as_float((__float_as_uint(s1) & 0xFFFFF000u) | j);
#pragma unroll
            for (int k = KNN - 1; k >= 1; --k) l0[k] = med3f(f0, l0[k-1], l0[k]);
            l0[0] = fminf(f0, l0[0]);
#pragma unroll
            for (int k = KNN - 1; k >= 1; --k) l1[k] = med3f(f1, l1[k-1], l1[k]);
            l1[0] = fminf(f1, l1[0]);
        }
    };

    // Double-buffered scan over this half's 64 candidates (rotated visit
    // order keeps each 16-lane phase on distinct bank-quads).
    {
        int g0 = split & 15;
        float4 XA = sx4[g0], YA = sy4[g0], ZA = sz4[g0];
#pragma unroll 1
        for (int t = 0; t < NG4; t += 2) {
            int g1 = (t + 1 + split) & 15;
            float4 XB = sx4[g1], YB = sy4[g1], ZB = sz4[g1];
            PROC(XA, YA, ZA, t);
            if (t + 2 < NG4) {
                int g2 = (t + 2 + split) & 15;
                XA = sx4[g2]; YA = sy4[g2]; ZA = sz4[g2];
            }
            PROC(XB, YB, ZB, t + 1);
        }
    }

    // ---- in-wave merge: 1 paired round, parity select, 4 single rounds ----
    merge_round(l0, 1);
    merge_round(l1, 1);
    const int sel = split & 1;
    float ml[KNN];
#pragma unroll
    for (int k = 0; k < KNN; ++k) ml[k] = sel ? l1[k] : l0[k];
    merge_round(ml, 2); merge_round(ml, 4); merge_round(ml, 8); merge_round(ml, 16);
    // even lanes hold (half's) q0 top-10, odd lanes q1's (sorted)

    // ---- cross-half merge in-place in qlists (lanes 0,1 of each group) ----
    if (half == 1 && split < 2) {
#pragma unroll
        for (int k = 0; k < KNN; ++k) qlists[qpair * 2 + split][k] = ml[k];
    }
    __syncthreads();
    if (half == 0 && split < 2) {
        float c[KNN];
#pragma unroll
        for (int i = 0; i < KNN; ++i)
            c[i] = fminf(ml[i], qlists[qpair * 2 + split][KNN - 1 - i]);
        SORT10(c);
#pragma unroll
        for (int k = 0; k < KNN; ++k) qlists[qpair * 2 + split][k] = c[k];
    }
    __syncthreads();

    // ---- epilogue: one query per group (32 groups = 32 queries) ----
    const int qi = qb + group;
    const float eqx = -2.f*sx[qi], eqy = -2.f*sy[qi], eqz = -2.f*sz[qi];

    // distributed changingrate: lanes 0..9 handle one neighbor each
    float crk = 0.0f;
    if (split < KNN) {
        int j = (int)(__float_as_uint(qlists[group][split]) & 0xFFFu);
        float nx = xb[qi*6+3], ny = xb[qi*6+4], nz = xb[qi*6+5];
        float mx = xb[j*6+3],  my_ = xb[j*6+4],  mz = xb[j*6+5];
        float cx = ny*mz - nz*my_;
        float cy = nz*mx - nx*mz;
        float cz = nx*my_ - ny*mx;
        float c1 = sqrtf(cx*cx + cy*cy + cz*cz);
        float px = nx*mx, py = ny*my_, pz = nz*mz;
        float c2 = sqrtf(px*px + py*py + pz*pz);
        crk = fminf(c1, c2);
    }
#pragma unroll
    for (int m = 1; m <= 8; m <<= 1) crk += __shfl_xor(crk, m, 64);

    // top-2 skeleton scores for qi (32-lane split)
    float t0v = BIG, t1v = BIG;
    for (int m = split; m < NSKEL; m += 32) {
        float4 c = sskl[m];
        float s = fmaf(eqz, c.z, fmaf(eqy, c.y, fmaf(eqx, c.x, c.w)));
        t1v = med3f(s, t0v, t1v);    // uses old t0v
        t0v = fminf(s, t0v);
    }
#pragma unroll
    for (int m = 1; m <= 16; m <<= 1) {
        float o0 = __shfl_xor(t0v, m, 64);
        float o1 = __shfl_xor(t1v, m, 64);
        float nv = fminf(fmaxf(t0v, o0), fminf(t1v, o1));
        t0v = fminf(t0v, o0); t1v = nv;
    }
    // d2 gap == score gap (|q|^2 cancels); owner: split 0 of each group
    float contrib = (split == 0) ? crk * (t1v - t0v) : 0.0f;
    contrib += __shfl_down(contrib, 32);   // combine the wave's 2 groups
    if ((tid & 63) == 0) part[tid >> 6] = contrib;
    __syncthreads();
    if (tid == 0) {
        float s = 0.0f;
#pragma unroll
        for (int i = 0; i < 16; ++i) s += part[i];
        atomicAdd(out, s);
    }

    // ---- skeleton self-NN term, one block per batch ----
    if ((blockIdx.x & 127) == 0) {
        float v = 0.0f;
        if (tid < NSKEL) {
            float4 sq = sskl[tid];
            float b0 = BIG, b1 = BIG; int i0 = 0, i1 = 0;
            for (int jj = 0; jj < NSKEL; ++jj) {
                float4 c = sskl[jj];
                float s = c.w - 2.0f*(sq.x*c.x + sq.y*c.y + sq.z*c.z);
                if (s < b0)      { b1 = b0; i1 = i0; b0 = s; i0 = jj; }
                else if (s < b1) { b1 = s; i1 = jj; }
            }
            float4 c = sskl[i1];                 // knn_skele[..., 1]
            float dx = sq.x - c.x, dy = sq.y - c.y, dz = sq.z - c.z;
            v = sqrtf(dx*dx + dy*dy + dz*dz);
        }
#pragma unroll
        for (int o = 32; o > 0; o >>= 1) v += __shfl_down(v, o);
        if ((tid & 63) == 0 && tid < 128) atomicAdd(out, -0.5f * v);
    }
}

extern "C" void kernel_launch(void* const* d_in, const int* in_sizes, int n_in,
                              void* d_out, int out_size, void* d_ws, size_t ws_size,
                              hipStream_t stream) {
    const float* xyz  = (const float*)d_in[0];
    // d_in[1] = num_class (== NSKEL), compile-time constant here
    const float* skel = (const float*)d_in[2];
    float* out = (float*)d_out;

    hipMemsetAsync(out, 0, sizeof(float), stream);
    voronoi_kernel<<<BATCH * 128, 1024, 0, stream>>>(xyz, skel, out);
}

// Round 12
// 44.764 us; speedup vs baseline: 1.9937x; 1.3807x over previous
//
#include <hip/hip_runtime.h>

#define BATCH  4
#define NPTS   4096
#define NSKEL  100
#define KNN    10
#define KL     5                  // per-lane list length (see k=5 risk calc)
#define QPB    32                 // queries per block (16 pairs x 2)
#define CPT    64                 // candidates per thread
#define CHSTR  68                 // padded chunk stride in floats (17 float4s)
#define BIG    3.0e38f

__device__ __forceinline__ float med3f(float a, float b, float c) {
#if __has_builtin(__builtin_amdgcn_fmed3f)
    return __builtin_amdgcn_fmed3f(a, b, c);
#else
    float d;
    asm("v_med3_f32 %0, %1, %2, %3" : "=v"(d) : "v"(a), "v"(b), "v"(c));
    return d;
#endif
}

#define CE(a,i,j) do { float _lo = fminf(a[i],a[j]); a[j] = fmaxf(a[i],a[j]); a[i] = _lo; } while (0)
// Bitonic-merge network for any bitonic 10-seq (BM(16) with -INF front pad);
// validated R3-R11 (absmax 0).
#define SORT10(c) do { \
    CE(c,0,8); CE(c,1,9); \
    CE(c,2,6); CE(c,3,7); CE(c,4,8); CE(c,5,9); \
    CE(c,2,4); CE(c,3,5); CE(c,6,8); CE(c,7,9); CE(c,0,1); \
    CE(c,2,3); CE(c,4,5); CE(c,6,7); CE(c,8,9); } while (0)

// Half-cleaner merge of two ascending 10-lists (keep 10 smallest) + re-sort.
__device__ __forceinline__ void merge_round(float l[KNN], int mask) {
    float c[KNN];
#pragma unroll
    for (int i = 0; i < KNN; ++i) {
        float o = __shfl_xor(l[KNN - 1 - i], mask, 64);
        c[i] = fminf(l[i], o);
    }
    SORT10(c);
#pragma unroll
    for (int i = 0; i < KNN; ++i) l[i] = c[i];
}

// padded index for global point id i (chunk i>>6 shifted by 4 floats each)
#define PIDXF(i) ((i) + (((i) >> 6) << 2))

// (1024,4): proven spill-free codegen (~40 VGPR). (1024,8) caps VGPR at 64
// and triggers catastrophic scratch spill (R8/R10). 44<=64 so HW may still
// co-reside 2 blocks/CU when LDS fits.
__global__ __launch_bounds__(1024, 4) void voronoi_kernel(const float* __restrict__ xyz,
                                                          const float* __restrict__ skel,
                                                          float* __restrict__ out) {
    __shared__ __align__(16) float sx[NPTS + 256];   // padded SoA, 17 KB each
    __shared__ __align__(16) float sy[NPTS + 256];
    __shared__ __align__(16) float sz[NPTS + 256];
    __shared__ float4 sskl[NSKEL];
    __shared__ float  qlists[QPB][KNN];
    __shared__ float  part[16];

    const int tid = threadIdx.x;
    const int b   = blockIdx.x >> 7;            // 128 blocks per batch
    const int qb  = (blockIdx.x & 127) * QPB;   // 32 queries per block
    const float* xb = xyz  + (size_t)b * NPTS * 6;
    const float* sb = skel + (size_t)b * NSKEL * 3;

    // Stage 2 points per iter via 3 coalesced float4 loads
    for (int p2 = tid; p2 < NPTS / 2; p2 += 1024) {
        const float4* row = (const float4*)(xb + p2 * 12);
        float4 A = row[0], Bv = row[1], Cv = row[2];
        int i0 = 2 * p2;           // even: i0 and i0+1 share a chunk
        int pi = PIDXF(i0);
        sx[pi]   = A.x;  sy[pi]   = A.y;  sz[pi]   = A.z;
        sx[pi+1] = Bv.z; sy[pi+1] = Bv.w; sz[pi+1] = Cv.x;
    }
    if (tid < NSKEL) {
        float x = sb[tid*3+0], y = sb[tid*3+1], z = sb[tid*3+2];
        sskl[tid] = make_float4(x, y, z, x*x + y*y + z*z);
    }
    __syncthreads();

    const int split = tid & 31;
    const int group = tid >> 5;            // 0..31
    const int half  = group >> 4;          // candidate half
    const int qpair = group & 15;          // query-pair id
    const int q0i   = qb + qpair * 2;
    // score = |c|^2 - 2 q.c (monotone map of d2; d2 gap == score gap)
    const float n0x = -2.f*sx[PIDXF(q0i)],   n0y = -2.f*sy[PIDXF(q0i)],   n0z = -2.f*sz[PIDXF(q0i)];
    const float n1x = -2.f*sx[PIDXF(q0i+1)], n1y = -2.f*sy[PIDXF(q0i+1)], n1z = -2.f*sz[PIDXF(q0i+1)];

    float l0[KL], l1[KL];
#pragma unroll
    for (int k = 0; k < KL; ++k) { l0[k] = BIG; l1[k] = BIG; }

    const int ch = split + (half << 5);    // chunk 0..63
    const unsigned jbc = (unsigned)(ch << 6);
    const unsigned HMASK = 0xFFFFF000u;
    const float4* sx4 = (const float4*)(sx + ch * CHSTR);
    const float4* sy4 = (const float4*)(sy + ch * CHSTR);
    const float4* sz4 = (const float4*)(sz + ch * CHSTR);

    // Fully-unrolled scan, static immediate-offset ds_reads, 1-ahead prefetch
    {
        float4 XA = sx4[0], YA = sy4[0], ZA = sz4[0];
#pragma unroll
        for (int g = 0; g < 16; ++g) {
            float4 XN, YN, ZN;
            if (g + 1 < 16) { XN = sx4[g+1]; YN = sy4[g+1]; ZN = sz4[g+1]; }
#pragma unroll
            for (int u = 0; u < 4; ++u) {
                float x = ((const float*)&XA)[u];
                float y = ((const float*)&YA)[u];
                float z = ((const float*)&ZA)[u];
                float w  = fmaf(z, z, fmaf(y, y, x * x));
                float s0 = fmaf(n0z, z, fmaf(n0y, y, fmaf(n0x, x, w)));
                float s1 = fmaf(n1z, z, fmaf(n1y, y, fmaf(n1x, x, w)));
                unsigned j = jbc | (unsigned)(g * 4 + u);
                float f0 = __uint_as_float((__float_as_uint(s0) & HMASK) | j);
                float f1 = __uint_as_float((__float_as_uint(s1) & HMASK) | j);
                // k=5 branchless insert (all slots use OLD values)
                l0[4] = med3f(f0, l0[3], l0[4]);
                l0[3] = med3f(f0, l0[2], l0[3]);
                l0[2] = med3f(f0, l0[1], l0[2]);
                l0[1] = med3f(f0, l0[0], l0[1]);
                l0[0] = fminf(f0, l0[0]);
                l1[4] = med3f(f1, l1[3], l1[4]);
                l1[3] = med3f(f1, l1[2], l1[3]);
                l1[2] = med3f(f1, l1[1], l1[2]);
                l1[1] = med3f(f1, l1[0], l1[1]);
                l1[0] = fminf(f1, l1[0]);
            }
            XA = XN; YA = YN; ZA = ZN;
        }
    }

    // ---- mask-1 merge: exact concat of pair's 5-lists -> bitonic -> sorted 10
    float c0[KNN], c1[KNN];
#pragma unroll
    for (int i = 0; i < KL; ++i) {
        c0[i] = l0[i];
        c0[KL + i] = __shfl_xor(l0[KL - 1 - i], 1, 64);  // neighbor desc
        c1[i] = l1[i];
        c1[KL + i] = __shfl_xor(l1[KL - 1 - i], 1, 64);
    }
    SORT10(c0);
    SORT10(c1);
    const int sel = split & 1;
    float ml[KNN];
#pragma unroll
    for (int k = 0; k < KNN; ++k) ml[k] = sel ? c1[k] : c0[k];
    merge_round(ml, 2); merge_round(ml, 4); merge_round(ml, 8); merge_round(ml, 16);
    // even lanes hold (half's) q0 top-10, odd lanes q1's (sorted)

    // ---- cross-half merge in-place in qlists (lanes 0,1 of each group) ----
    if (half == 1 && split < 2) {
#pragma unroll
        for (int k = 0; k < KNN; ++k) qlists[qpair * 2 + split][k] = ml[k];
    }
    __syncthreads();
    if (half == 0 && split < 2) {
        float c[KNN];
#pragma unroll
        for (int i = 0; i < KNN; ++i)
            c[i] = fminf(ml[i], qlists[qpair * 2 + split][KNN - 1 - i]);
        SORT10(c);
#pragma unroll
        for (int k = 0; k < KNN; ++k) qlists[qpair * 2 + split][k] = c[k];
    }
    __syncthreads();

    // ---- epilogue: one query per group (32 groups = 32 queries) ----
    const int qi = qb + group;
    const int qp = PIDXF(qi);
    const float eqx = -2.f*sx[qp], eqy = -2.f*sy[qp], eqz = -2.f*sz[qp];

    // distributed changingrate: lanes 0..9 handle one neighbor each
    float crk = 0.0f;
    if (split < KNN) {
        int j = (int)(__float_as_uint(qlists[group][split]) & 0xFFFu);
        float nx = xb[qi*6+3], ny = xb[qi*6+4], nz = xb[qi*6+5];
        float mx = xb[j*6+3],  my_ = xb[j*6+4],  mz = xb[j*6+5];
        float cx = ny*mz - nz*my_;
        float cy = nz*mx - nx*mz;
        float cz = nx*my_ - ny*mx;
        float c1 = sqrtf(cx*cx + cy*cy + cz*cz);
        float px = nx*mx, py = ny*my_, pz = nz*mz;
        float c2 = sqrtf(px*px + py*py + pz*pz);
        crk = fminf(c1, c2);
    }
#pragma unroll
    for (int m = 1; m <= 8; m <<= 1) crk += __shfl_xor(crk, m, 64);

    // top-2 skeleton scores for qi (32-lane split)
    float t0v = BIG, t1v = BIG;
    for (int m = split; m < NSKEL; m += 32) {
        float4 c = sskl[m];
        float s = fmaf(eqz, c.z, fmaf(eqy, c.y, fmaf(eqx, c.x, c.w)));
        t1v = med3f(s, t0v, t1v);    // uses old t0v
        t0v = fminf(s, t0v);
    }
#pragma unroll
    for (int m = 1; m <= 16; m <<= 1) {
        float o0 = __shfl_xor(t0v, m, 64);
        float o1 = __shfl_xor(t1v, m, 64);
        float nv = fminf(fmaxf(t0v, o0), fminf(t1v, o1));
        t0v = fminf(t0v, o0); t1v = nv;
    }
    // d2 gap == score gap (|q|^2 cancels); owner: split 0 of each group
    float contrib = (split == 0) ? crk * (t1v - t0v) : 0.0f;
    contrib += __shfl_down(contrib, 32);   // combine the wave's 2 groups
    if ((tid & 63) == 0) part[tid >> 6] = contrib;
    __syncthreads();
    if (tid == 0) {
        float s = 0.0f;
#pragma unroll
        for (int i = 0; i < 16; ++i) s += part[i];
        atomicAdd(out, s);
    }

    // ---- skeleton self-NN term, one block per batch ----
    if ((blockIdx.x & 127) == 0) {
        float v = 0.0f;
        if (tid < NSKEL) {
            float4 sq = sskl[tid];
            float b0 = BIG, b1 = BIG; int i0 = 0, i1 = 0;
            for (int jj = 0; jj < NSKEL; ++jj) {
                float4 c = sskl[jj];
                float s = c.w - 2.0f*(sq.x*c.x + sq.y*c.y + sq.z*c.z);
                if (s < b0)      { b1 = b0; i1 = i0; b0 = s; i0 = jj; }
                else if (s < b1) { b1 = s; i1 = jj; }
            }
            float4 c = sskl[i1];                 // knn_skele[..., 1]
            float dx = sq.x - c.x, dy = sq.y - c.y, dz = sq.z - c.z;
            v = sqrtf(dx*dx + dy*dy + dz*dz);
        }
#pragma unroll
        for (int o = 32; o > 0; o >>= 1) v += __shfl_down(v, o);
        if ((tid & 63) == 0 && tid < 128) atomicAdd(out, -0.5f * v);
    }
}

extern "C" void kernel_launch(void* const* d_in, const int* in_sizes, int n_in,
                              void* d_out, int out_size, void* d_ws, size_t ws_size,
                              hipStream_t stream) {
    const float* xyz  = (const float*)d_in[0];
    // d_in[1] = num_class (== NSKEL), compile-time constant here
    const float* skel = (const float*)d_in[2];
    float* out = (float*)d_out;

    hipMemsetAsync(out, 0, sizeof(float), stream);
    voronoi_kernel<<<BATCH * 128, 1024, 0, stream>>>(xyz, skel, out);
}

// Round 13
// 44.278 us; speedup vs baseline: 2.0156x; 1.0110x over previous
//
#include <hip/hip_runtime.h>

#define BATCH  4
#define NPTS   4096
#define NSKEL  100
#define KNN    10
#define KL     5                  // per-lane list length (k=5 risk ~3e-3 events/run)
#define QPB    32                 // queries per block (16 pairs x 2)
#define CPT    64                 // candidates per thread
#define CHSTR  68                 // padded chunk stride in floats (17 float4s)
#define BIG    3.0e38f

__device__ __forceinline__ float med3f(float a, float b, float c) {
#if __has_builtin(__builtin_amdgcn_fmed3f)
    return __builtin_amdgcn_fmed3f(a, b, c);
#else
    float d;
    asm("v_med3_f32 %0, %1, %2, %3" : "=v"(d) : "v"(a), "v"(b), "v"(c));
    return d;
#endif
}

#define CE(a,i,j) do { float _lo = fminf(a[i],a[j]); a[j] = fmaxf(a[i],a[j]); a[i] = _lo; } while (0)
// Bitonic-merge network for any bitonic 10-seq (BM(16) with -INF front pad);
// validated R3-R12 (absmax 0).
#define SORT10(c) do { \
    CE(c,0,8); CE(c,1,9); \
    CE(c,2,6); CE(c,3,7); CE(c,4,8); CE(c,5,9); \
    CE(c,2,4); CE(c,3,5); CE(c,6,8); CE(c,7,9); CE(c,0,1); \
    CE(c,2,3); CE(c,4,5); CE(c,6,7); CE(c,8,9); } while (0)

// Half-cleaner merge of two ascending 10-lists (keep 10 smallest) + re-sort.
__device__ __forceinline__ void merge_round(float l[KNN], int mask) {
    float c[KNN];
#pragma unroll
    for (int i = 0; i < KNN; ++i) {
        float o = __shfl_xor(l[KNN - 1 - i], mask, 64);
        c[i] = fminf(l[i], o);
    }
    SORT10(c);
#pragma unroll
    for (int i = 0; i < KNN; ++i) l[i] = c[i];
}

// padded index for global point id i (chunk i>>6 shifted by 4 floats each)
#define PIDXF(i) ((i) + (((i) >> 6) << 2))

// Plain __launch_bounds__(1024): no min-waves arg. (1024,4) made the
// allocator pin arch-VGPRs at 32 and shuffle the merge state through
// AGPRs (v_accvgpr_* are VALU ops: R12 showed 2x the static VALU count
// with VGPR_Count=32, no scratch). (1024,8) spilled to scratch (R8/R10).
__global__ __launch_bounds__(1024) void voronoi_kernel(const float* __restrict__ xyz,
                                                       const float* __restrict__ skel,
                                                       float* __restrict__ out) {
    __shared__ __align__(16) float sx[NPTS + 256];   // padded SoA, 17 KB each
    __shared__ __align__(16) float sy[NPTS + 256];
    __shared__ __align__(16) float sz[NPTS + 256];
    __shared__ float4 sskl[NSKEL];
    __shared__ float  qlists[QPB][KNN];
    __shared__ float  part[16];

    const int tid = threadIdx.x;
    const int b   = blockIdx.x >> 7;            // 128 blocks per batch
    const int qb  = (blockIdx.x & 127) * QPB;   // 32 queries per block
    const float* xb = xyz  + (size_t)b * NPTS * 6;
    const float* sb = skel + (size_t)b * NSKEL * 3;

    // Stage 2 points per iter via 3 coalesced float4 loads
    for (int p2 = tid; p2 < NPTS / 2; p2 += 1024) {
        const float4* row = (const float4*)(xb + p2 * 12);
        float4 A = row[0], Bv = row[1], Cv = row[2];
        int i0 = 2 * p2;           // even: i0 and i0+1 share a chunk
        int pi = PIDXF(i0);
        sx[pi]   = A.x;  sy[pi]   = A.y;  sz[pi]   = A.z;
        sx[pi+1] = Bv.z; sy[pi+1] = Bv.w; sz[pi+1] = Cv.x;
    }
    if (tid < NSKEL) {
        float x = sb[tid*3+0], y = sb[tid*3+1], z = sb[tid*3+2];
        sskl[tid] = make_float4(x, y, z, x*x + y*y + z*z);
    }
    __syncthreads();

    const int split = tid & 31;
    const int group = tid >> 5;            // 0..31
    const int half  = group >> 4;          // candidate half
    const int qpair = group & 15;          // query-pair id
    const int q0i   = qb + qpair * 2;
    // score = |c|^2 - 2 q.c (monotone map of d2; d2 gap == score gap)
    const float n0x = -2.f*sx[PIDXF(q0i)],   n0y = -2.f*sy[PIDXF(q0i)],   n0z = -2.f*sz[PIDXF(q0i)];
    const float n1x = -2.f*sx[PIDXF(q0i+1)], n1y = -2.f*sy[PIDXF(q0i+1)], n1z = -2.f*sz[PIDXF(q0i+1)];

    float l0[KL], l1[KL];
#pragma unroll
    for (int k = 0; k < KL; ++k) { l0[k] = BIG; l1[k] = BIG; }

    const int ch = split + (half << 5);    // chunk 0..63
    const unsigned jbc = (unsigned)(ch << 6);
    const unsigned HMASK = 0xFFFFF000u;
    const float4* sx4 = (const float4*)(sx + ch * CHSTR);
    const float4* sy4 = (const float4*)(sy + ch * CHSTR);
    const float4* sz4 = (const float4*)(sz + ch * CHSTR);

    // Fully-unrolled scan; static immediate-offset ds_reads; compiler
    // handles scheduling/pipelining (no manual prefetch copies).
#pragma unroll
    for (int g = 0; g < 16; ++g) {
        float4 XA = sx4[g], YA = sy4[g], ZA = sz4[g];
#pragma unroll
        for (int u = 0; u < 4; ++u) {
            float x = ((const float*)&XA)[u];
            float y = ((const float*)&YA)[u];
            float z = ((const float*)&ZA)[u];
            float w  = fmaf(z, z, fmaf(y, y, x * x));
            float s0 = fmaf(n0z, z, fmaf(n0y, y, fmaf(n0x, x, w)));
            float s1 = fmaf(n1z, z, fmaf(n1y, y, fmaf(n1x, x, w)));
            unsigned j = jbc | (unsigned)(g * 4 + u);
            float f0 = __uint_as_float((__float_as_uint(s0) & HMASK) | j);
            float f1 = __uint_as_float((__float_as_uint(s1) & HMASK) | j);
            // k=5 branchless insert (all slots use OLD values)
            l0[4] = med3f(f0, l0[3], l0[4]);
            l0[3] = med3f(f0, l0[2], l0[3]);
            l0[2] = med3f(f0, l0[1], l0[2]);
            l0[1] = med3f(f0, l0[0], l0[1]);
            l0[0] = fminf(f0, l0[0]);
            l1[4] = med3f(f1, l1[3], l1[4]);
            l1[3] = med3f(f1, l1[2], l1[3]);
            l1[2] = med3f(f1, l1[1], l1[2]);
            l1[1] = med3f(f1, l1[0], l1[1]);
            l1[0] = fminf(f1, l1[0]);
        }
    }

    // ---- mask-1 merge: exact concat of pair's 5-lists -> bitonic -> sorted 10
    float c0[KNN], c1[KNN];
#pragma unroll
    for (int i = 0; i < KL; ++i) {
        c0[i] = l0[i];
        c0[KL + i] = __shfl_xor(l0[KL - 1 - i], 1, 64);  // neighbor desc
        c1[i] = l1[i];
        c1[KL + i] = __shfl_xor(l1[KL - 1 - i], 1, 64);
    }
    SORT10(c0);
    SORT10(c1);
    const int sel = split & 1;
    float ml[KNN];
#pragma unroll
    for (int k = 0; k < KNN; ++k) ml[k] = sel ? c1[k] : c0[k];
    merge_round(ml, 2); merge_round(ml, 4); merge_round(ml, 8); merge_round(ml, 16);
    // even lanes hold (half's) q0 top-10, odd lanes q1's (sorted)

    // ---- cross-half merge in qlists; final result needs only the SET of
    //      top-10 (changingrate sums over all 10), so skip the re-sort ----
    if (half == 1 && split < 2) {
#pragma unroll
        for (int k = 0; k < KNN; ++k) qlists[qpair * 2 + split][k] = ml[k];
    }
    __syncthreads();
    if (half == 0 && split < 2) {
        float c[KNN];
#pragma unroll
        for (int i = 0; i < KNN; ++i)
            c[i] = fminf(ml[i], qlists[qpair * 2 + split][KNN - 1 - i]);
#pragma unroll
        for (int k = 0; k < KNN; ++k) qlists[qpair * 2 + split][k] = c[k];
    }
    __syncthreads();

    // ---- epilogue: one query per group (32 groups = 32 queries) ----
    const int qi = qb + group;
    const int qp = PIDXF(qi);
    const float eqx = -2.f*sx[qp], eqy = -2.f*sy[qp], eqz = -2.f*sz[qp];

    // distributed changingrate: lanes 0..9 handle one neighbor each
    float crk = 0.0f;
    if (split < KNN) {
        int j = (int)(__float_as_uint(qlists[group][split]) & 0xFFFu);
        float nx = xb[qi*6+3], ny = xb[qi*6+4], nz = xb[qi*6+5];
        float mx = xb[j*6+3],  my_ = xb[j*6+4],  mz = xb[j*6+5];
        float cx = ny*mz - nz*my_;
        float cy = nz*mx - nx*mz;
        float cz = nx*my_ - ny*mx;
        float c1 = sqrtf(cx*cx + cy*cy + cz*cz);
        float px = nx*mx, py = ny*my_, pz = nz*mz;
        float c2 = sqrtf(px*px + py*py + pz*pz);
        crk = fminf(c1, c2);
    }
#pragma unroll
    for (int m = 1; m <= 8; m <<= 1) crk += __shfl_xor(crk, m, 64);

    // top-2 skeleton scores for qi (32-lane split)
    float t0v = BIG, t1v = BIG;
    for (int m = split; m < NSKEL; m += 32) {
        float4 c = sskl[m];
        float s = fmaf(eqz, c.z, fmaf(eqy, c.y, fmaf(eqx, c.x, c.w)));
        t1v = med3f(s, t0v, t1v);    // uses old t0v
        t0v = fminf(s, t0v);
    }
#pragma unroll
    for (int m = 1; m <= 16; m <<= 1) {
        float o0 = __shfl_xor(t0v, m, 64);
        float o1 = __shfl_xor(t1v, m, 64);
        float nv = fminf(fmaxf(t0v, o0), fminf(t1v, o1));
        t0v = fminf(t0v, o0); t1v = nv;
    }
    // d2 gap == score gap (|q|^2 cancels); owner: split 0 of each group
    float contrib = (split == 0) ? crk * (t1v - t0v) : 0.0f;
    contrib += __shfl_down(contrib, 32);   // combine the wave's 2 groups
    if ((tid & 63) == 0) part[tid >> 6] = contrib;
    __syncthreads();
    if (tid == 0) {
        float s = 0.0f;
#pragma unroll
        for (int i = 0; i < 16; ++i) s += part[i];
        atomicAdd(out, s);
    }

    // ---- skeleton self-NN term, one block per batch ----
    if ((blockIdx.x & 127) == 0) {
        float v = 0.0f;
        if (tid < NSKEL) {
            float4 sq = sskl[tid];
            float b0 = BIG, b1 = BIG; int i0 = 0, i1 = 0;
            for (int jj = 0; jj < NSKEL; ++jj) {
                float4 c = sskl[jj];
                float s = c.w - 2.0f*(sq.x*c.x + sq.y*c.y + sq.z*c.z);
                if (s < b0)      { b1 = b0; i1 = i0; b0 = s; i0 = jj; }
                else if (s < b1) { b1 = s; i1 = jj; }
            }
            float4 c = sskl[i1];                 // knn_skele[..., 1]
            float dx = sq.x - c.x, dy = sq.y - c.y, dz = sq.z - c.z;
            v = sqrtf(dx*dx + dy*dy + dz*dz);
        }
#pragma unroll
        for (int o = 32; o > 0; o >>= 1) v += __shfl_down(v, o);
        if ((tid & 63) == 0 && tid < 128) atomicAdd(out, -0.5f * v);
    }
}

extern "C" void kernel_launch(void* const* d_in, const int* in_sizes, int n_in,
                              void* d_out, int out_size, void* d_ws, size_t ws_size,
                              hipStream_t stream) {
    const float* xyz  = (const float*)d_in[0];
    // d_in[1] = num_class (== NSKEL), compile-time constant here
    const float* skel = (const float*)d_in[2];
    float* out = (float*)d_out;

    hipMemsetAsync(out, 0, sizeof(float), stream);
    voronoi_kernel<<<BATCH * 128, 1024, 0, stream>>>(xyz, skel, out);
}

// Round 14
// 41.862 us; speedup vs baseline: 2.1319x; 1.0577x over previous
//
#include <hip/hip_runtime.h>

#define BATCH  4
#define NPTS   4096
#define NSKEL  100
#define KNN    10
#define KL     4                  // per-lane list length (risk ~0.24 tiny events/run)
#define QPB    32                 // queries per block (16 pairs x 2)
#define CPT    64                 // candidates per thread
#define CPAD   65                 // padded chunk stride in float4s (bank de-conflict)
#define BIG    3.0e38f

__device__ __forceinline__ float med3f(float a, float b, float c) {
#if __has_builtin(__builtin_amdgcn_fmed3f)
    return __builtin_amdgcn_fmed3f(a, b, c);
#else
    float d;
    asm("v_med3_f32 %0, %1, %2, %3" : "=v"(d) : "v"(a), "v"(b), "v"(c));
    return d;
#endif
}

#define CE(a,i,j) do { float _lo = fminf(a[i],a[j]); a[j] = fmaxf(a[i],a[j]); a[i] = _lo; } while (0)
// Sorts any bitonic 10-seq (validated R3-R13, absmax 0 throughout)
#define SORT10(c) do { \
    CE(c,0,8); CE(c,1,9); \
    CE(c,2,6); CE(c,3,7); CE(c,4,8); CE(c,5,9); \
    CE(c,2,4); CE(c,3,5); CE(c,6,8); CE(c,7,9); CE(c,0,1); \
    CE(c,2,3); CE(c,4,5); CE(c,6,7); CE(c,8,9); } while (0)
// Bitonic merger BM(8): sorts any bitonic 8-seq (3 stages, 12 CE)
#define BM8(c) do { \
    CE(c,0,4); CE(c,1,5); CE(c,2,6); CE(c,3,7); \
    CE(c,0,2); CE(c,1,3); CE(c,4,6); CE(c,5,7); \
    CE(c,0,1); CE(c,2,3); CE(c,4,5); CE(c,6,7); } while (0)

// Half-cleaner merge of two ascending 10-lists (keep 10 smallest) + re-sort.
__device__ __forceinline__ void merge_round(float l[KNN], int mask) {
    float c[KNN];
#pragma unroll
    for (int i = 0; i < KNN; ++i) {
        float o = __shfl_xor(l[KNN - 1 - i], mask, 64);
        c[i] = fminf(l[i], o);
    }
    SORT10(c);
#pragma unroll
    for (int i = 0; i < KNN; ++i) l[i] = c[i];
}

// padded float4 index for global point id i (chunk i>>6 gets +1 float4 each)
#define PIDX(i) ((i) + ((i) >> 6))

__global__ __launch_bounds__(1024) void voronoi_kernel(const float* __restrict__ xyz,
                                                       const float* __restrict__ skel,
                                                       float* __restrict__ out) {
    __shared__ float4 spts[NPTS + 64];   // AoS x,y,z,|p|^2, padded: 65 KB
    __shared__ float4 sskl[NSKEL];
    __shared__ float  qlists[QPB][KNN];
    __shared__ float  part[16];

    const int tid = threadIdx.x;
    const int b   = blockIdx.x >> 7;            // 128 blocks per batch
    const int qb  = (blockIdx.x & 127) * QPB;   // 32 queries per block
    const float* xb = xyz  + (size_t)b * NPTS * 6;
    const float* sb = skel + (size_t)b * NSKEL * 3;

    // Stage 2 points per iter via 3 coalesced float4 loads
    for (int p2 = tid; p2 < NPTS / 2; p2 += 1024) {
        const float4* row = (const float4*)(xb + p2 * 12);
        float4 A = row[0], Bv = row[1], Cv = row[2];
        int i0 = 2 * p2;           // even: i0, i0+1 share a chunk
        spts[PIDX(i0)]     = make_float4(A.x, A.y, A.z,
                                         fmaf(A.z, A.z, fmaf(A.y, A.y, A.x * A.x)));
        spts[PIDX(i0 + 1)] = make_float4(Bv.z, Bv.w, Cv.x,
                                         fmaf(Cv.x, Cv.x, fmaf(Bv.w, Bv.w, Bv.z * Bv.z)));
    }
    if (tid < NSKEL) {
        float x = sb[tid*3+0], y = sb[tid*3+1], z = sb[tid*3+2];
        sskl[tid] = make_float4(x, y, z, x*x + y*y + z*z);
    }
    __syncthreads();

    const int split = tid & 31;
    const int group = tid >> 5;            // 0..31
    const int half  = group >> 4;          // candidate half
    const int qpair = group & 15;          // query-pair id
    const int q0i   = qb + qpair * 2;
    const float4 Q0 = spts[PIDX(q0i)];
    const float4 Q1 = spts[PIDX(q0i + 1)];
    // score = |c|^2 - 2 q.c (monotone map of d2; d2 gap == score gap)
    const float n0x = -2.f*Q0.x, n0y = -2.f*Q0.y, n0z = -2.f*Q0.z;
    const float n1x = -2.f*Q1.x, n1y = -2.f*Q1.y, n1z = -2.f*Q1.z;

    float l0[KL], l1[KL];
#pragma unroll
    for (int k = 0; k < KL; ++k) { l0[k] = BIG; l1[k] = BIG; }

    const int ch = split + (half << 5);    // chunk 0..63
    const unsigned jbc = (unsigned)(ch << 6);
    const unsigned HMASK = 0xFFFFF000u;
    const float4* chunk = spts + ch * CPAD;  // base bank phase-distinct per 8 ch

    // Fully-unrolled scan; 1 ds_read_b128 per candidate, static offsets.
#pragma unroll
    for (int g = 0; g < CPT; ++g) {
        float4 cc = chunk[g];
        float s0 = fmaf(n0z, cc.z, fmaf(n0y, cc.y, fmaf(n0x, cc.x, cc.w)));
        float s1 = fmaf(n1z, cc.z, fmaf(n1y, cc.y, fmaf(n1x, cc.x, cc.w)));
        unsigned j = jbc | (unsigned)g;
        float f0 = __uint_as_float((__float_as_uint(s0) & HMASK) | j);
        float f1 = __uint_as_float((__float_as_uint(s1) & HMASK) | j);
        // KL=4 branchless insert (all slots use OLD values)
        l0[3] = med3f(f0, l0[2], l0[3]);
        l0[2] = med3f(f0, l0[1], l0[2]);
        l0[1] = med3f(f0, l0[0], l0[1]);
        l0[0] = fminf(f0, l0[0]);
        l1[3] = med3f(f1, l1[2], l1[3]);
        l1[2] = med3f(f1, l1[1], l1[2]);
        l1[1] = med3f(f1, l1[0], l1[1]);
        l1[0] = fminf(f1, l1[0]);
    }

    // ---- mask-1 merge: concat my asc-4 + neighbor desc-4 = bitonic 8 ----
    float c0[2 * KL], c1[2 * KL];
#pragma unroll
    for (int i = 0; i < KL; ++i) {
        c0[i] = l0[i];
        c0[KL + i] = __shfl_xor(l0[KL - 1 - i], 1, 64);
        c1[i] = l1[i];
        c1[KL + i] = __shfl_xor(l1[KL - 1 - i], 1, 64);
    }
    BM8(c0);
    BM8(c1);
    const int sel = split & 1;
    float a8[2 * KL];
#pragma unroll
    for (int k = 0; k < 2 * KL; ++k) a8[k] = sel ? c1[k] : c0[k];
    // even lanes: sorted-8 for q0 over their pair's 128 cands; odd: q1

    // ---- mask-2: merge two asc-8s, keep 10 smallest (INF-padded
    //      half-cleaner -> cyclically-bitonic 10 -> SORT10) ----
    float ml[KNN];
    {
        float b8[2 * KL];
#pragma unroll
        for (int k = 0; k < 2 * KL; ++k) b8[k] = __shfl_xor(a8[k], 2, 64);
        ml[0] = a8[0];
        ml[1] = a8[1];
#pragma unroll
        for (int i = 2; i <= 7; ++i) ml[i] = fminf(a8[i], b8[9 - i]);
        ml[8] = b8[1];
        ml[9] = b8[0];
        SORT10(ml);
    }
    merge_round(ml, 4); merge_round(ml, 8); merge_round(ml, 16);
    // even lanes hold (half's) q0 top-10, odd lanes q1's (sorted)

    // ---- cross-half merge in qlists (lanes 0,1 of each group); final
    //      consumer needs only the SET, so no re-sort ----
    if (half == 1 && split < 2) {
#pragma unroll
        for (int k = 0; k < KNN; ++k) qlists[qpair * 2 + split][k] = ml[k];
    }
    __syncthreads();
    if (half == 0 && split < 2) {
        float c[KNN];
#pragma unroll
        for (int i = 0; i < KNN; ++i)
            c[i] = fminf(ml[i], qlists[qpair * 2 + split][KNN - 1 - i]);
#pragma unroll
        for (int k = 0; k < KNN; ++k) qlists[qpair * 2 + split][k] = c[k];
    }
    __syncthreads();

    // ---- epilogue: one query per group (32 groups = 32 queries) ----
    const int qi = qb + group;
    const float4 Qe = spts[PIDX(qi)];
    const float eqx = -2.f*Qe.x, eqy = -2.f*Qe.y, eqz = -2.f*Qe.z;

    // distributed changingrate: lanes 0..9 handle one neighbor each
    float crk = 0.0f;
    if (split < KNN) {
        int j = (int)(__float_as_uint(qlists[group][split]) & 0xFFFu);
        float nx = xb[qi*6+3], ny = xb[qi*6+4], nz = xb[qi*6+5];
        float mx = xb[j*6+3],  my_ = xb[j*6+4],  mz = xb[j*6+5];
        float cx = ny*mz - nz*my_;
        float cy = nz*mx - nx*mz;
        float cz = nx*my_ - ny*mx;
        float c1 = sqrtf(cx*cx + cy*cy + cz*cz);
        float px = nx*mx, py = ny*my_, pz = nz*mz;
        float c2 = sqrtf(px*px + py*py + pz*pz);
        crk = fminf(c1, c2);
    }
#pragma unroll
    for (int m = 1; m <= 8; m <<= 1) crk += __shfl_xor(crk, m, 64);

    // top-2 skeleton scores for qi (32-lane split)
    float t0v = BIG, t1v = BIG;
    for (int m = split; m < NSKEL; m += 32) {
        float4 c = sskl[m];
        float s = fmaf(eqz, c.z, fmaf(eqy, c.y, fmaf(eqx, c.x, c.w)));
        t1v = med3f(s, t0v, t1v);    // uses old t0v
        t0v = fminf(s, t0v);
    }
#pragma unroll
    for (int m = 1; m <= 16; m <<= 1) {
        float o0 = __shfl_xor(t0v, m, 64);
        float o1 = __shfl_xor(t1v, m, 64);
        float nv = fminf(fmaxf(t0v, o0), fminf(t1v, o1));
        t0v = fminf(t0v, o0); t1v = nv;
    }
    // d2 gap == score gap (|q|^2 cancels); owner: split 0 of each group
    float contrib = (split == 0) ? crk * (t1v - t0v) : 0.0f;
    contrib += __shfl_down(contrib, 32);   // combine the wave's 2 groups
    if ((tid & 63) == 0) part[tid >> 6] = contrib;
    __syncthreads();
    if (tid == 0) {
        float s = 0.0f;
#pragma unroll
        for (int i = 0; i < 16; ++i) s += part[i];
        atomicAdd(out, s);
    }

    // ---- skeleton self-NN term, one block per batch ----
    if ((blockIdx.x & 127) == 0) {
        float v = 0.0f;
        if (tid < NSKEL) {
            float4 sq = sskl[tid];
            float b0 = BIG, b1 = BIG; int i0 = 0, i1 = 0;
            for (int jj = 0; jj < NSKEL; ++jj) {
                float4 c = sskl[jj];
                float s = c.w - 2.0f*(sq.x*c.x + sq.y*c.y + sq.z*c.z);
                if (s < b0)      { b1 = b0; i1 = i0; b0 = s; i0 = jj; }
                else if (s < b1) { b1 = s; i1 = jj; }
            }
            float4 c = sskl[i1];                 // knn_skele[..., 1]
            float dx = sq.x - c.x, dy = sq.y - c.y, dz = sq.z - c.z;
            v = sqrtf(dx*dx + dy*dy + dz*dz);
        }
#pragma unroll
        for (int o = 32; o > 0; o >>= 1) v += __shfl_down(v, o);
        if ((tid & 63) == 0 && tid < 128) atomicAdd(out, -0.5f * v);
    }
}

extern "C" void kernel_launch(void* const* d_in, const int* in_sizes, int n_in,
                              void* d_out, int out_size, void* d_ws, size_t ws_size,
                              hipStream_t stream) {
    const float* xyz  = (const float*)d_in[0];
    // d_in[1] = num_class (== NSKEL), compile-time constant here
    const float* skel = (const float*)d_in[2];
    float* out = (float*)d_out;

    hipMemsetAsync(out, 0, sizeof(float), stream);
    voronoi_kernel<<<BATCH * 128, 1024, 0, stream>>>(xyz, skel, out);
}

// Round 15
// 39.918 us; speedup vs baseline: 2.2358x; 1.0487x over previous
//
#include <hip/hip_runtime.h>

#define BATCH  4
#define NPTS   4096
#define NSKEL  100
#define KNN    10
#define KL     3                  // per-lane list length (~12 tiny events/run, each <=1 abs)
#define QPB    32                 // queries per block (16 pairs x 2)
#define CPT    64                 // candidates per thread
#define CPAD   65                 // padded chunk stride in float4s (bank de-conflict)
#define BIG    3.0e38f

__device__ __forceinline__ float med3f(float a, float b, float c) {
#if __has_builtin(__builtin_amdgcn_fmed3f)
    return __builtin_amdgcn_fmed3f(a, b, c);
#else
    float d;
    asm("v_med3_f32 %0, %1, %2, %3" : "=v"(d) : "v"(a), "v"(b), "v"(c));
    return d;
#endif
}

#define CE(a,i,j) do { float _lo = fminf(a[i],a[j]); a[j] = fmaxf(a[i],a[j]); a[i] = _lo; } while (0)
// Sorts any (cyclically-)bitonic 10-seq (validated R3-R14, absmax 0 throughout)
#define SORT10(c) do { \
    CE(c,0,8); CE(c,1,9); \
    CE(c,2,6); CE(c,3,7); CE(c,4,8); CE(c,5,9); \
    CE(c,2,4); CE(c,3,5); CE(c,6,8); CE(c,7,9); CE(c,0,1); \
    CE(c,2,3); CE(c,4,5); CE(c,6,7); CE(c,8,9); } while (0)
// Bitonic merger BM(8): sorts any bitonic 8-seq (3 stages, 12 CE)
#define BM8(c) do { \
    CE(c,0,4); CE(c,1,5); CE(c,2,6); CE(c,3,7); \
    CE(c,0,2); CE(c,1,3); CE(c,4,6); CE(c,5,7); \
    CE(c,0,1); CE(c,2,3); CE(c,4,5); CE(c,6,7); } while (0)

// Half-cleaner merge of two ascending 10-lists (keep 10 smallest) + re-sort.
__device__ __forceinline__ void merge_round(float l[KNN], int mask) {
    float c[KNN];
#pragma unroll
    for (int i = 0; i < KNN; ++i) {
        float o = __shfl_xor(l[KNN - 1 - i], mask, 64);
        c[i] = fminf(l[i], o);
    }
    SORT10(c);
#pragma unroll
    for (int i = 0; i < KNN; ++i) l[i] = c[i];
}

// padded float4 index for global point id i (chunk i>>6 gets +1 float4 each)
#define PIDX(i) ((i) + ((i) >> 6))

__global__ __launch_bounds__(1024) void voronoi_kernel(const float* __restrict__ xyz,
                                                       const float* __restrict__ skel,
                                                       float* __restrict__ out) {
    __shared__ float4 spts[NPTS + 64];   // AoS x,y,z,|p|^2, padded: 65 KB
    __shared__ float4 sskl[NSKEL];
    __shared__ float  qlists[QPB][KNN];
    __shared__ float  part[16];

    const int tid = threadIdx.x;
    const int b   = blockIdx.x >> 7;            // 128 blocks per batch
    const int qb  = (blockIdx.x & 127) * QPB;   // 32 queries per block
    const float* xb = xyz  + (size_t)b * NPTS * 6;
    const float* sb = skel + (size_t)b * NSKEL * 3;

    // Stage 2 points per iter via 3 coalesced float4 loads
    for (int p2 = tid; p2 < NPTS / 2; p2 += 1024) {
        const float4* row = (const float4*)(xb + p2 * 12);
        float4 A = row[0], Bv = row[1], Cv = row[2];
        int i0 = 2 * p2;           // even: i0, i0+1 share a chunk
        spts[PIDX(i0)]     = make_float4(A.x, A.y, A.z,
                                         fmaf(A.z, A.z, fmaf(A.y, A.y, A.x * A.x)));
        spts[PIDX(i0 + 1)] = make_float4(Bv.z, Bv.w, Cv.x,
                                         fmaf(Cv.x, Cv.x, fmaf(Bv.w, Bv.w, Bv.z * Bv.z)));
    }
    if (tid < NSKEL) {
        float x = sb[tid*3+0], y = sb[tid*3+1], z = sb[tid*3+2];
        sskl[tid] = make_float4(x, y, z, x*x + y*y + z*z);
    }
    __syncthreads();

    const int split = tid & 31;
    const int group = tid >> 5;            // 0..31
    const int half  = group >> 4;          // candidate half
    const int qpair = group & 15;          // query-pair id
    const int q0i   = qb + qpair * 2;
    const float4 Q0 = spts[PIDX(q0i)];
    const float4 Q1 = spts[PIDX(q0i + 1)];
    // score = |c|^2 - 2 q.c (monotone map of d2; d2 gap == score gap)
    const float n0x = -2.f*Q0.x, n0y = -2.f*Q0.y, n0z = -2.f*Q0.z;
    const float n1x = -2.f*Q1.x, n1y = -2.f*Q1.y, n1z = -2.f*Q1.z;

    float l0[KL], l1[KL];
#pragma unroll
    for (int k = 0; k < KL; ++k) { l0[k] = BIG; l1[k] = BIG; }

    const int ch = split + (half << 5);    // chunk 0..63
    const unsigned jbc = (unsigned)(ch << 6);
    const unsigned HMASK = 0xFFFFF000u;
    const float4* chunk = spts + ch * CPAD;  // base bank phase-distinct per 8 ch

    // Fully-unrolled scan; 1 ds_read_b128 per candidate, static offsets.
#pragma unroll
    for (int g = 0; g < CPT; ++g) {
        float4 cc = chunk[g];
        float s0 = fmaf(n0z, cc.z, fmaf(n0y, cc.y, fmaf(n0x, cc.x, cc.w)));
        float s1 = fmaf(n1z, cc.z, fmaf(n1y, cc.y, fmaf(n1x, cc.x, cc.w)));
        unsigned j = jbc | (unsigned)g;
        float f0 = __uint_as_float((__float_as_uint(s0) & HMASK) | j);
        float f1 = __uint_as_float((__float_as_uint(s1) & HMASK) | j);
        // KL=3 branchless insert (all slots use OLD values)
        l0[2] = med3f(f0, l0[1], l0[2]);
        l0[1] = med3f(f0, l0[0], l0[1]);
        l0[0] = fminf(f0, l0[0]);
        l1[2] = med3f(f1, l1[1], l1[2]);
        l1[1] = med3f(f1, l1[0], l1[1]);
        l1[0] = fminf(f1, l1[0]);
    }

    // ---- mask-1 merge: {a0,a1,a2,BIG,BIG,b2,b1,b0} is bitonic-8 -> BM8;
    //      real sorted-6 lands in c[0..5] ----
    float c0[8], c1[8];
    c0[0] = l0[0]; c0[1] = l0[1]; c0[2] = l0[2]; c0[3] = BIG; c0[4] = BIG;
    c0[5] = __shfl_xor(l0[2], 1, 64);
    c0[6] = __shfl_xor(l0[1], 1, 64);
    c0[7] = __shfl_xor(l0[0], 1, 64);
    c1[0] = l1[0]; c1[1] = l1[1]; c1[2] = l1[2]; c1[3] = BIG; c1[4] = BIG;
    c1[5] = __shfl_xor(l1[2], 1, 64);
    c1[6] = __shfl_xor(l1[1], 1, 64);
    c1[7] = __shfl_xor(l1[0], 1, 64);
    BM8(c0);
    BM8(c1);
    const int sel = split & 1;
    float a6[6];
#pragma unroll
    for (int k = 0; k < 6; ++k) a6[k] = sel ? c1[k] : c0[k];
    // even lanes: sorted top-6 (of pair's 128 cands) for q0; odd: q1

    // ---- mask-2: merge two asc-6s, keep 10 of 12 (BIG-pad half-cleaner;
    //      only 6 shfl + 2 min needed) -> SORT10 ----
    float ml[KNN];
    {
        float B6[6];
#pragma unroll
        for (int k = 0; k < 6; ++k) B6[k] = __shfl_xor(a6[k], 2, 64);
        ml[0] = a6[0]; ml[1] = a6[1]; ml[2] = a6[2]; ml[3] = a6[3];
        ml[4] = fminf(a6[4], B6[5]);
        ml[5] = fminf(a6[5], B6[4]);
        ml[6] = B6[3]; ml[7] = B6[2]; ml[8] = B6[1]; ml[9] = B6[0];
        SORT10(ml);
    }
    merge_round(ml, 4); merge_round(ml, 8); merge_round(ml, 16);
    // even lanes hold (half's) q0 top-10, odd lanes q1's (sorted)

    // ---- cross-half merge in qlists (lanes 0,1 of each group); final
    //      consumer needs only the SET, so no re-sort ----
    if (half == 1 && split < 2) {
#pragma unroll
        for (int k = 0; k < KNN; ++k) qlists[qpair * 2 + split][k] = ml[k];
    }
    __syncthreads();
    if (half == 0 && split < 2) {
        float c[KNN];
#pragma unroll
        for (int i = 0; i < KNN; ++i)
            c[i] = fminf(ml[i], qlists[qpair * 2 + split][KNN - 1 - i]);
#pragma unroll
        for (int k = 0; k < KNN; ++k) qlists[qpair * 2 + split][k] = c[k];
    }
    __syncthreads();

    // ---- epilogue: one query per group (32 groups = 32 queries) ----
    const int qi = qb + group;
    const float4 Qe = spts[PIDX(qi)];
    const float eqx = -2.f*Qe.x, eqy = -2.f*Qe.y, eqz = -2.f*Qe.z;

    // distributed changingrate: lanes 0..9 handle one neighbor each
    float crk = 0.0f;
    if (split < KNN) {
        int j = (int)(__float_as_uint(qlists[group][split]) & 0xFFFu);
        float nx = xb[qi*6+3], ny = xb[qi*6+4], nz = xb[qi*6+5];
        float mx = xb[j*6+3],  my_ = xb[j*6+4],  mz = xb[j*6+5];
        float cx = ny*mz - nz*my_;
        float cy = nz*mx - nx*mz;
        float cz = nx*my_ - ny*mx;
        float c1 = sqrtf(cx*cx + cy*cy + cz*cz);
        float px = nx*mx, py = ny*my_, pz = nz*mz;
        float c2 = sqrtf(px*px + py*py + pz*pz);
        crk = fminf(c1, c2);
    }
#pragma unroll
    for (int m = 1; m <= 8; m <<= 1) crk += __shfl_xor(crk, m, 64);

    // top-2 skeleton scores for qi (32-lane split)
    float t0v = BIG, t1v = BIG;
    for (int m = split; m < NSKEL; m += 32) {
        float4 c = sskl[m];
        float s = fmaf(eqz, c.z, fmaf(eqy, c.y, fmaf(eqx, c.x, c.w)));
        t1v = med3f(s, t0v, t1v);    // uses old t0v
        t0v = fminf(s, t0v);
    }
#pragma unroll
    for (int m = 1; m <= 16; m <<= 1) {
        float o0 = __shfl_xor(t0v, m, 64);
        float o1 = __shfl_xor(t1v, m, 64);
        float nv = fminf(fmaxf(t0v, o0), fminf(t1v, o1));
        t0v = fminf(t0v, o0); t1v = nv;
    }
    // d2 gap == score gap (|q|^2 cancels); owner: split 0 of each group
    float contrib = (split == 0) ? crk * (t1v - t0v) : 0.0f;
    contrib += __shfl_down(contrib, 32);   // combine the wave's 2 groups
    if ((tid & 63) == 0) part[tid >> 6] = contrib;
    __syncthreads();
    if (tid == 0) {
        float s = 0.0f;
#pragma unroll
        for (int i = 0; i < 16; ++i) s += part[i];
        atomicAdd(out, s);
    }

    // ---- skeleton self-NN term, one block per batch ----
    if ((blockIdx.x & 127) == 0) {
        float v = 0.0f;
        if (tid < NSKEL) {
            float4 sq = sskl[tid];
            float b0 = BIG, b1 = BIG; int i0 = 0, i1 = 0;
            for (int jj = 0; jj < NSKEL; ++jj) {
                float4 c = sskl[jj];
                float s = c.w - 2.0f*(sq.x*c.x + sq.y*c.y + sq.z*c.z);
                if (s < b0)      { b1 = b0; i1 = i0; b0 = s; i0 = jj; }
                else if (s < b1) { b1 = s; i1 = jj; }
            }
            float4 c = sskl[i1];                 // knn_skele[..., 1]
            float dx = sq.x - c.x, dy = sq.y - c.y, dz = sq.z - c.z;
            v = sqrtf(dx*dx + dy*dy + dz*dz);
        }
#pragma unroll
        for (int o = 32; o > 0; o >>= 1) v += __shfl_down(v, o);
        if ((tid & 63) == 0 && tid < 128) atomicAdd(out, -0.5f * v);
    }
}

extern "C" void kernel_launch(void* const* d_in, const int* in_sizes, int n_in,
                              void* d_out, int out_size, void* d_ws, size_t ws_size,
                              hipStream_t stream) {
    const float* xyz  = (const float*)d_in[0];
    // d_in[1] = num_class (== NSKEL), compile-time constant here
    const float* skel = (const float*)d_in[2];
    float* out = (float*)d_out;

    hipMemsetAsync(out, 0, sizeof(float), stream);
    voronoi_kernel<<<BATCH * 128, 1024, 0, stream>>>(xyz, skel, out);
}